// Round 14
// baseline (478.806 us; speedup 1.0000x reference)
//
#include <hip/hip_runtime.h>
#include <hip/hip_bf16.h>

#define IN_DIM 64
#define OUT_DIM 64

typedef float nt_f4 __attribute__((ext_vector_type(4)));   // for nontemporal builtins
typedef int   nt_i2 __attribute__((ext_vector_type(2)));   // for nontemporal int2 store

// ---------------------------------------------------------------------------
// Canary: launched FIRST; absorbs any first-dispatch counter-attribution
// artifact (reset/poison traffic). Writes offsets[n]=nE (scan3 rewrites it).
// ---------------------------------------------------------------------------
__global__ void canary_kernel(int* __restrict__ offsets, int n, int nE) {
    if (threadIdx.x == 0 && blockIdx.x == 0) offsets[n] = nE;
}

// ---------------------------------------------------------------------------
// Kernel 1: h = ReLU(features @ q_w + q_b); counts = 0.
// Register-blocked: 4 rows x 16 cols per thread (validated round 13).
// ---------------------------------------------------------------------------
__global__ __launch_bounds__(256) void proj_kernel(
    const float4* __restrict__ feat4, const float4* __restrict__ qw4,
    const float4* __restrict__ qb4, float4* __restrict__ h4,
    int* __restrict__ counts, int n) {
    const size_t gtid = blockIdx.x * (size_t)256 + threadIdx.x;
    const int rg   = (int)(gtid >> 2);       // 4-row group
    const int sub  = (int)(gtid & 3);        // 16-col chunk
    const int row0 = rg * 4;
    if (row0 >= n) return;
    const int rmax = (n - row0 < 4) ? (n - row0) : 4;

    float4 acc[4][4];                        // [row][m]
    #pragma unroll
    for (int r = 0; r < 4; ++r)
        #pragma unroll
        for (int m = 0; m < 4; ++m) acc[r][m] = qb4[sub * 4 + m];

    for (int k4 = 0; k4 < 16; ++k4) {
        float4 xv[4];
        #pragma unroll
        for (int r = 0; r < 4; ++r) {
            const int rr = (r < rmax) ? r : 0;
            xv[r] = feat4[(size_t)(row0 + rr) * 16 + k4];
        }
        float4 w[4][4];                      // [j][m]
        #pragma unroll
        for (int j = 0; j < 4; ++j)
            #pragma unroll
            for (int m = 0; m < 4; ++m)
                w[j][m] = qw4[(k4 * 4 + j) * 16 + sub * 4 + m];
        #pragma unroll
        for (int j = 0; j < 4; ++j) {
            #pragma unroll
            for (int r = 0; r < 4; ++r) {
                const float xs = (j == 0) ? xv[r].x : (j == 1) ? xv[r].y
                               : (j == 2) ? xv[r].z : xv[r].w;
                #pragma unroll
                for (int m = 0; m < 4; ++m) {
                    acc[r][m].x = fmaf(xs, w[j][m].x, acc[r][m].x);
                    acc[r][m].y = fmaf(xs, w[j][m].y, acc[r][m].y);
                    acc[r][m].z = fmaf(xs, w[j][m].z, acc[r][m].z);
                    acc[r][m].w = fmaf(xs, w[j][m].w, acc[r][m].w);
                }
            }
        }
    }

    #pragma unroll
    for (int r = 0; r < 4; ++r) {
        if (r >= rmax) break;
        if (sub == 0) counts[row0 + r] = 0;
        #pragma unroll
        for (int m = 0; m < 4; ++m) {
            float4 v = acc[r][m];
            v.x = fmaxf(v.x, 0.f); v.y = fmaxf(v.y, 0.f);
            v.z = fmaxf(v.z, 0.f); v.w = fmaxf(v.w, 0.f);
            h4[(size_t)(row0 + r) * 16 + sub * 4 + m] = v;
        }
    }
}

// ---------------------------------------------------------------------------
// CSR build: histogram of dst
// ---------------------------------------------------------------------------
__global__ __launch_bounds__(256) void count_kernel(
    const int* __restrict__ dst, int* __restrict__ counts, int n, int nE) {
    const int e = blockIdx.x * 256 + threadIdx.x;
    if (e >= nE) return;
    int d = __builtin_nontemporal_load(&dst[e]);
    d = ((unsigned)d < (unsigned)n) ? d : 0;
    atomicAdd(&counts[d], 1);
}

// per-block inclusive scan -> exclusive offsets + block sums
__global__ __launch_bounds__(256) void scan1_kernel(
    const int* __restrict__ counts, int* __restrict__ offsets,
    int* __restrict__ blocksums, int n) {
    __shared__ int s[256];
    const int tid = threadIdx.x;
    const int i = blockIdx.x * 256 + tid;
    const int v = (i < n) ? counts[i] : 0;
    s[tid] = v;
    __syncthreads();
    #pragma unroll
    for (int off = 1; off < 256; off <<= 1) {
        const int t = (tid >= off) ? s[tid - off] : 0;
        __syncthreads();
        s[tid] += t;
        __syncthreads();
    }
    if (i < n) offsets[i] = s[tid] - v;          // exclusive within block
    if (tid == 255) blocksums[blockIdx.x] = s[255];
}

// single-block exclusive scan of block sums (nb <= 512)
__global__ __launch_bounds__(512) void scan2_kernel(int* __restrict__ blocksums, int nb) {
    __shared__ int s[512];
    const int tid = threadIdx.x;
    const int v = (tid < nb) ? blocksums[tid] : 0;
    s[tid] = v;
    __syncthreads();
    #pragma unroll
    for (int off = 1; off < 512; off <<= 1) {
        const int t = (tid >= off) ? s[tid - off] : 0;
        __syncthreads();
        s[tid] += t;
        __syncthreads();
    }
    if (tid < nb) blocksums[tid] = s[tid] - v;   // exclusive
}

__global__ __launch_bounds__(256) void scan3_kernel(
    int* __restrict__ offsets, int* __restrict__ cursor,
    const int* __restrict__ blocksums, int n, int nE) {
    const int i = blockIdx.x * 256 + threadIdx.x;
    if (i < n) {
        const int o = offsets[i] + blocksums[blockIdx.x];
        offsets[i] = o;
        cursor[i]  = o;
    }
    if (i == 0) offsets[n] = nE;
}

// bucket edges by dst: pack {src, alpha} into one 8B record.
// Round-13 counters: WRITE_SIZE = 100.6MB = nE x 64B -> each scattered 8B
// store dirtied a full line. Nontemporal store to avoid line allocation
// (sector-granular writeback); predicted WRITE_SIZE -> ~51-64MB.
__global__ __launch_bounds__(256) void fill_kernel(
    const int* __restrict__ dst, const int* __restrict__ src,
    const float* __restrict__ alpha, int* __restrict__ cursor,
    int2* __restrict__ edges_s, int n, int nE) {
    const int e = blockIdx.x * 256 + threadIdx.x;
    if (e >= nE) return;
    int d = __builtin_nontemporal_load(&dst[e]);
    d = ((unsigned)d < (unsigned)n) ? d : 0;
    const int s = __builtin_nontemporal_load(&src[e]);
    const float a = __builtin_nontemporal_load(&alpha[e]);
    const int p = atomicAdd(&cursor[d], 1);
    if ((unsigned)p < (unsigned)nE) {
        nt_i2 rec;
        rec.x = s;
        rec.y = __float_as_int(a);
        __builtin_nontemporal_store(rec, (nt_i2*)&edges_s[p]);
    }
}

// ---------------------------------------------------------------------------
// Aggregation (atomic-free): one wave per node; 8 edges in parallel
// (8 lanes per edge, each lane covers 2 float4 chunks -> 16 independent
// gather chains per wave; round-13 had only 4 chains).
// ---------------------------------------------------------------------------
__global__ __launch_bounds__(256) void agg_kernel(
    const float4* __restrict__ h4, const int2* __restrict__ edges_s,
    const int* __restrict__ offsets, float4* __restrict__ hn4, int n, int nE) {
    const size_t gtid = blockIdx.x * (size_t)256 + threadIdx.x;
    const int v    = (int)(gtid >> 6);
    const int lane = (int)(gtid & 63);
    const int g    = lane >> 3;        // which of 8 parallel edges
    const int c4   = lane & 7;         // float4 chunks c4 and c4+8
    if (v >= n) return;

    int b  = offsets[v];
    int e1 = offsets[v + 1];
    if (b < 0) b = 0;
    if (e1 > nE) e1 = nE;

    float4 accL = make_float4(0.f, 0.f, 0.f, 0.f);
    float4 accH = make_float4(0.f, 0.f, 0.f, 0.f);
    for (int j = b + g; j < e1; j += 8) {
        const int2 ed = edges_s[j];
        int s = ed.x;
        s = ((unsigned)s < (unsigned)n) ? s : 0;
        const float a = __int_as_float(ed.y);
        const float4 lo = h4[(size_t)s * 16 + c4];
        const float4 hi = h4[(size_t)s * 16 + c4 + 8];
        accL.x = fmaf(lo.x, a, accL.x); accL.y = fmaf(lo.y, a, accL.y);
        accL.z = fmaf(lo.z, a, accL.z); accL.w = fmaf(lo.w, a, accL.w);
        accH.x = fmaf(hi.x, a, accH.x); accH.y = fmaf(hi.y, a, accH.y);
        accH.z = fmaf(hi.z, a, accH.z); accH.w = fmaf(hi.w, a, accH.w);
    }
    // reduce the 8 edge-group partials (lanes ^8, ^16, ^32)
    #pragma unroll
    for (int off = 8; off <= 32; off <<= 1) {
        accL.x += __shfl_xor(accL.x, off, 64); accL.y += __shfl_xor(accL.y, off, 64);
        accL.z += __shfl_xor(accL.z, off, 64); accL.w += __shfl_xor(accL.w, off, 64);
        accH.x += __shfl_xor(accH.x, off, 64); accH.y += __shfl_xor(accH.y, off, 64);
        accH.z += __shfl_xor(accH.z, off, 64); accH.w += __shfl_xor(accH.w, off, 64);
    }

    if (g == 0) {
        hn4[(size_t)v * 16 + c4]     = accL;
        hn4[(size_t)v * 16 + c4 + 8] = accH;
    }
}

// ---------------------------------------------------------------------------
// Fallback (only if ws too small): atomic scatter. hn must be pre-zeroed.
// ---------------------------------------------------------------------------
__global__ __launch_bounds__(256) void zero_kernel(float* __restrict__ p, size_t cnt) {
    const size_t i = blockIdx.x * (size_t)256 + threadIdx.x;
    if (i < cnt) p[i] = 0.f;
}
__global__ __launch_bounds__(256) void scatter_kernel(
    const float4* __restrict__ h4, const float* __restrict__ alpha,
    const int* __restrict__ src, const int* __restrict__ dst,
    float* __restrict__ hn, int nE) {
    const size_t gtid = blockIdx.x * (size_t)256 + threadIdx.x;
    const int eid = (int)(gtid >> 4);
    const int c4  = (int)(gtid & 15);
    if (eid >= nE) return;
    const int   s = src[eid];
    const int   d = dst[eid];
    const float a = alpha[eid];
    const float4 v = h4[(size_t)s * 16 + c4];
    float* p = &hn[(size_t)d * IN_DIM + c4 * 4];
    unsafeAtomicAdd(p + 0, v.x * a);
    unsafeAtomicAdd(p + 1, v.y * a);
    unsafeAtomicAdd(p + 2, v.z * a);
    unsafeAtomicAdd(p + 3, v.w * a);
}

// ---------------------------------------------------------------------------
// Kernel 3: z = ReLU(concat([h, hn]) @ w_w + w_b); out = z / ||z||_2.
// Register-blocked 4 rows x 16 cols per thread (validated round 13).
// ---------------------------------------------------------------------------
__global__ __launch_bounds__(256) void out_kernel(
    const float4* __restrict__ h4, const float4* __restrict__ hn4,
    const float4* __restrict__ ww4, const float4* __restrict__ wb4,
    float4* __restrict__ out4, int n) {
    const size_t gtid = blockIdx.x * (size_t)256 + threadIdx.x;
    const int rg   = (int)(gtid >> 2);
    const int sub  = (int)(gtid & 3);
    const int row0 = rg * 4;
    if (row0 >= n) return;
    const int rmax = (n - row0 < 4) ? (n - row0) : 4;

    float4 acc[4][4];
    #pragma unroll
    for (int r = 0; r < 4; ++r)
        #pragma unroll
        for (int m = 0; m < 4; ++m) acc[r][m] = wb4[sub * 4 + m];

    // phase 0: h @ w_w[0:64];  phase 1: hn @ w_w[64:128]
    #pragma unroll
    for (int ph = 0; ph < 2; ++ph) {
        const float4* __restrict__ x4 = (ph == 0) ? h4 : hn4;
        for (int k4 = 0; k4 < 16; ++k4) {
            float4 xv[4];
            #pragma unroll
            for (int r = 0; r < 4; ++r) {
                const int rr = (r < rmax) ? r : 0;
                xv[r] = x4[(size_t)(row0 + rr) * 16 + k4];
            }
            float4 w[4][4];
            #pragma unroll
            for (int j = 0; j < 4; ++j)
                #pragma unroll
                for (int m = 0; m < 4; ++m)
                    w[j][m] = ww4[(ph * 64 + k4 * 4 + j) * 16 + sub * 4 + m];
            #pragma unroll
            for (int j = 0; j < 4; ++j) {
                #pragma unroll
                for (int r = 0; r < 4; ++r) {
                    const float xs = (j == 0) ? xv[r].x : (j == 1) ? xv[r].y
                                   : (j == 2) ? xv[r].z : xv[r].w;
                    #pragma unroll
                    for (int m = 0; m < 4; ++m) {
                        acc[r][m].x = fmaf(xs, w[j][m].x, acc[r][m].x);
                        acc[r][m].y = fmaf(xs, w[j][m].y, acc[r][m].y);
                        acc[r][m].z = fmaf(xs, w[j][m].z, acc[r][m].z);
                        acc[r][m].w = fmaf(xs, w[j][m].w, acc[r][m].w);
                    }
                }
            }
        }
    }

    // ReLU + per-row sum of squares; reduce across the 4 subs (lanes ^1, ^2)
    float sq[4];
    #pragma unroll
    for (int r = 0; r < 4; ++r) {
        float s = 0.f;
        #pragma unroll
        for (int m = 0; m < 4; ++m) {
            acc[r][m].x = fmaxf(acc[r][m].x, 0.f);
            acc[r][m].y = fmaxf(acc[r][m].y, 0.f);
            acc[r][m].z = fmaxf(acc[r][m].z, 0.f);
            acc[r][m].w = fmaxf(acc[r][m].w, 0.f);
            s = fmaf(acc[r][m].x, acc[r][m].x, s);
            s = fmaf(acc[r][m].y, acc[r][m].y, s);
            s = fmaf(acc[r][m].z, acc[r][m].z, s);
            s = fmaf(acc[r][m].w, acc[r][m].w, s);
        }
        sq[r] = s;
    }
    #pragma unroll
    for (int r = 0; r < 4; ++r) {
        sq[r] += __shfl_xor(sq[r], 1, 64);
        sq[r] += __shfl_xor(sq[r], 2, 64);
    }

    #pragma unroll
    for (int r = 0; r < 4; ++r) {
        if (r >= rmax) break;
        const float inv = 1.0f / sqrtf(sq[r]);
        #pragma unroll
        for (int m = 0; m < 4; ++m) {
            nt_f4 v;
            v.x = acc[r][m].x * inv; v.y = acc[r][m].y * inv;
            v.z = acc[r][m].z * inv; v.w = acc[r][m].w * inv;
            __builtin_nontemporal_store(
                v, (nt_f4*)&out4[(size_t)(row0 + r) * 16 + sub * 4 + m]);
        }
    }
}

extern "C" void kernel_launch(void* const* d_in, const int* in_sizes, int n_in,
                              void* d_out, int out_size, void* d_ws, size_t ws_size,
                              hipStream_t stream) {
    const float* feat  = (const float*)d_in[0];
    const float* qw    = (const float*)d_in[1];
    const float* qb    = (const float*)d_in[2];
    const float* ww    = (const float*)d_in[3];
    const float* wb    = (const float*)d_in[4];
    const float* alpha = (const float*)d_in[5];
    const int*   src   = (const int*)d_in[6];
    const int*   dst   = (const int*)d_in[7];
    float* out = (float*)d_out;

    const int n  = in_sizes[0] / IN_DIM;   // 100000
    const int nE = in_sizes[5];            // 1600000
    const int NB = (n + 255) / 256;        // 391

    // workspace layout
    float* h        = (float*)d_ws;                    // n*64 f32
    float* hn       = h + (size_t)n * IN_DIM;          // n*64 f32
    int*   counts   = (int*)(hn + (size_t)n * IN_DIM); // n
    int*   offsets  = counts + n;                      // n+1
    int*   cursor   = offsets + (n + 1);               // n
    int*   blocksums= cursor + n;                      // NB
    // align edges_s to 8B
    char*  raw      = (char*)(blocksums + NB);
    int2*  edges_s  = (int2*)(((uintptr_t)raw + 7) & ~(uintptr_t)7);   // nE int2
    const size_t needed = (size_t)((char*)(edges_s + nE) - (char*)d_ws);
    const bool do_csr = ws_size >= needed;

    // 0) canary (attribution probe)
    canary_kernel<<<1, 64, 0, stream>>>(offsets, n, nE);

    // 1) projection + zero counts (4 rows x 16 cols per thread)
    {
        const long long t = ((long long)(n + 3) / 4) * 4;
        proj_kernel<<<(int)((t + 255) / 256), 256, 0, stream>>>(
            (const float4*)feat, (const float4*)qw, (const float4*)qb,
            (float4*)h, counts, n);
    }

    if (do_csr) {
        // 2) CSR build + atomic-free aggregation (canonical)
        count_kernel<<<(nE + 255) / 256, 256, 0, stream>>>(dst, counts, n, nE);
        scan1_kernel<<<NB, 256, 0, stream>>>(counts, offsets, blocksums, n);
        scan2_kernel<<<1, 512, 0, stream>>>(blocksums, NB);
        scan3_kernel<<<NB, 256, 0, stream>>>(offsets, cursor, blocksums, n, nE);
        fill_kernel<<<(nE + 255) / 256, 256, 0, stream>>>(
            dst, src, alpha, cursor, edges_s, n, nE);
        agg_kernel<<<(int)(((long long)n * 64 + 255) / 256), 256, 0, stream>>>(
            (const float4*)h, edges_s, offsets, (float4*)hn, n, nE);
    } else {
        // fallback: zero + atomic scatter
        const size_t cnt = (size_t)n * IN_DIM;
        zero_kernel<<<(int)((cnt + 255) / 256), 256, 0, stream>>>(hn, cnt);
        scatter_kernel<<<(int)(((long long)nE * 16 + 255) / 256), 256, 0, stream>>>(
            (const float4*)h, alpha, src, dst, hn, nE);
    }

    // 3) concat GEMV + ReLU + L2 normalize (4 rows x 16 cols per thread)
    {
        const long long t = ((long long)(n + 3) / 4) * 4;
        out_kernel<<<(int)((t + 255) / 256), 256, 0, stream>>>(
            (const float4*)h, (const float4*)hn, (const float4*)ww,
            (const float4*)wb, (float4*)out, n);
    }
}

// Round 15
// 443.572 us; speedup vs baseline: 1.0794x; 1.0794x over previous
//
#include <hip/hip_runtime.h>
#include <hip/hip_bf16.h>

#define IN_DIM 64
#define OUT_DIM 64
#define EPB 4096          // edges per block in partition pass A
#define BSHIFT 9          // 512 nodes per coarse bucket

typedef float nt_f4 __attribute__((ext_vector_type(4)));   // for nontemporal builtins
typedef unsigned long long u64;

// ---------------------------------------------------------------------------
// Canary: launched FIRST; absorbs any first-dispatch counter-attribution
// artifact. Writes offsets[n]=nE (scan3 rewrites it identically).
// ---------------------------------------------------------------------------
__global__ void canary_kernel(int* __restrict__ offsets, int n, int nE) {
    if (threadIdx.x == 0 && blockIdx.x == 0) offsets[n] = nE;
}

// ---------------------------------------------------------------------------
// Kernel 1: h = ReLU(features @ q_w + q_b); counts = 0.
// Register-blocked 4 rows x 16 cols per thread (validated round 13).
// ---------------------------------------------------------------------------
__global__ __launch_bounds__(256) void proj_kernel(
    const float4* __restrict__ feat4, const float4* __restrict__ qw4,
    const float4* __restrict__ qb4, float4* __restrict__ h4,
    int* __restrict__ counts, int n) {
    const size_t gtid = blockIdx.x * (size_t)256 + threadIdx.x;
    const int rg   = (int)(gtid >> 2);
    const int sub  = (int)(gtid & 3);
    const int row0 = rg * 4;
    if (row0 >= n) return;
    const int rmax = (n - row0 < 4) ? (n - row0) : 4;

    float4 acc[4][4];
    #pragma unroll
    for (int r = 0; r < 4; ++r)
        #pragma unroll
        for (int m = 0; m < 4; ++m) acc[r][m] = qb4[sub * 4 + m];

    for (int k4 = 0; k4 < 16; ++k4) {
        float4 xv[4];
        #pragma unroll
        for (int r = 0; r < 4; ++r) {
            const int rr = (r < rmax) ? r : 0;
            xv[r] = feat4[(size_t)(row0 + rr) * 16 + k4];
        }
        float4 w[4][4];
        #pragma unroll
        for (int j = 0; j < 4; ++j)
            #pragma unroll
            for (int m = 0; m < 4; ++m)
                w[j][m] = qw4[(k4 * 4 + j) * 16 + sub * 4 + m];
        #pragma unroll
        for (int j = 0; j < 4; ++j) {
            #pragma unroll
            for (int r = 0; r < 4; ++r) {
                const float xs = (j == 0) ? xv[r].x : (j == 1) ? xv[r].y
                               : (j == 2) ? xv[r].z : xv[r].w;
                #pragma unroll
                for (int m = 0; m < 4; ++m) {
                    acc[r][m].x = fmaf(xs, w[j][m].x, acc[r][m].x);
                    acc[r][m].y = fmaf(xs, w[j][m].y, acc[r][m].y);
                    acc[r][m].z = fmaf(xs, w[j][m].z, acc[r][m].z);
                    acc[r][m].w = fmaf(xs, w[j][m].w, acc[r][m].w);
                }
            }
        }
    }

    #pragma unroll
    for (int r = 0; r < 4; ++r) {
        if (r >= rmax) break;
        if (sub == 0) counts[row0 + r] = 0;
        #pragma unroll
        for (int m = 0; m < 4; ++m) {
            float4 v = acc[r][m];
            v.x = fmaxf(v.x, 0.f); v.y = fmaxf(v.y, 0.f);
            v.z = fmaxf(v.z, 0.f); v.w = fmaxf(v.w, 0.f);
            h4[(size_t)(row0 + r) * 16 + sub * 4 + m] = v;
        }
    }
}

// ---------------------------------------------------------------------------
// CSR build: histogram of dst
// ---------------------------------------------------------------------------
__global__ __launch_bounds__(256) void count_kernel(
    const int* __restrict__ dst, int* __restrict__ counts, int n, int nE) {
    const int e = blockIdx.x * 256 + threadIdx.x;
    if (e >= nE) return;
    int d = dst[e];
    d = ((unsigned)d < (unsigned)n) ? d : 0;
    atomicAdd(&counts[d], 1);
}

__global__ __launch_bounds__(256) void scan1_kernel(
    const int* __restrict__ counts, int* __restrict__ offsets,
    int* __restrict__ blocksums, int n) {
    __shared__ int s[256];
    const int tid = threadIdx.x;
    const int i = blockIdx.x * 256 + tid;
    const int v = (i < n) ? counts[i] : 0;
    s[tid] = v;
    __syncthreads();
    #pragma unroll
    for (int off = 1; off < 256; off <<= 1) {
        const int t = (tid >= off) ? s[tid - off] : 0;
        __syncthreads();
        s[tid] += t;
        __syncthreads();
    }
    if (i < n) offsets[i] = s[tid] - v;
    if (tid == 255) blocksums[blockIdx.x] = s[255];
}

__global__ __launch_bounds__(512) void scan2_kernel(int* __restrict__ blocksums, int nb) {
    __shared__ int s[512];
    const int tid = threadIdx.x;
    const int v = (tid < nb) ? blocksums[tid] : 0;
    s[tid] = v;
    __syncthreads();
    #pragma unroll
    for (int off = 1; off < 512; off <<= 1) {
        const int t = (tid >= off) ? s[tid - off] : 0;
        __syncthreads();
        s[tid] += t;
        __syncthreads();
    }
    if (tid < nb) blocksums[tid] = s[tid] - v;
}

// finalize offsets/cursor; also init per-bucket cursors (bucket = node>>BSHIFT)
__global__ __launch_bounds__(256) void scan3_kernel(
    int* __restrict__ offsets, int* __restrict__ cursor,
    const int* __restrict__ blocksums, int* __restrict__ bcur,
    int n, int nE) {
    const int i = blockIdx.x * 256 + threadIdx.x;
    if (i < n) {
        const int o = offsets[i] + blocksums[blockIdx.x];
        offsets[i] = o;
        cursor[i]  = o;
        if ((i & ((1 << BSHIFT) - 1)) == 0) bcur[i >> BSHIFT] = o;
    }
    if (i == 0) offsets[n] = nE;
}

// ---------------------------------------------------------------------------
// Partition pass A: bin edges into coarse-bucket regions of edges_s order.
// Each block: 4096 edges -> LDS histogram over <=256 buckets -> LDS scan ->
// reorder records bucket-major in LDS -> flush contiguous runs to tmp.
// Record = {dst:17 | src:17 | alpha_bits>>2:30} packed in u64.
// ---------------------------------------------------------------------------
__global__ __launch_bounds__(256) void partA_kernel(
    const int* __restrict__ dst, const int* __restrict__ src,
    const float* __restrict__ alpha, int* __restrict__ bcur,
    u64* __restrict__ tmp, int n, int nE, int nbuk) {
    __shared__ int hist[256];
    __shared__ int lofs[256];
    __shared__ int lcur[256];
    __shared__ int gbase[256];
    __shared__ u64 stage[EPB];
    __shared__ unsigned short sbuk[EPB];

    const int tid = threadIdx.x;
    const int e0  = blockIdx.x * EPB;
    const int cnt = (nE - e0 < EPB) ? (nE - e0) : EPB;

    hist[tid] = 0;
    __syncthreads();

    // pass 1: histogram
    for (int i = tid; i < cnt; i += 256) {
        int d = dst[e0 + i];
        d = ((unsigned)d < (unsigned)n) ? d : 0;
        atomicAdd(&hist[d >> BSHIFT], 1);
    }
    __syncthreads();

    // block-wide exclusive scan of hist (Hillis-Steele inclusive, then -v)
    const int v = hist[tid];
    lofs[tid] = v;
    __syncthreads();
    #pragma unroll
    for (int off = 1; off < 256; off <<= 1) {
        const int t = (tid >= off) ? lofs[tid - off] : 0;
        __syncthreads();
        lofs[tid] += t;
        __syncthreads();
    }
    const int excl = lofs[tid] - v;
    __syncthreads();
    lofs[tid] = excl;
    lcur[tid] = excl;
    if (tid < nbuk) gbase[tid] = atomicAdd(&bcur[tid], v);
    __syncthreads();

    // pass 2: reorder into LDS stage (bucket-major)
    for (int i = tid; i < cnt; i += 256) {
        int d = dst[e0 + i];
        d = ((unsigned)d < (unsigned)n) ? d : 0;
        const int s = src[e0 + i];
        const unsigned ab = __float_as_uint(alpha[e0 + i]) >> 2;
        const int b = d >> BSHIFT;
        int lp = atomicAdd(&lcur[b], 1);
        lp = ((unsigned)lp < (unsigned)EPB) ? lp : 0;
        stage[lp] = (u64)(d & 0x1FFFF) | ((u64)(s & 0x1FFFF) << 17)
                  | ((u64)ab << 34);
        sbuk[lp]  = (unsigned short)b;
    }
    __syncthreads();

    // flush: contiguous per-bucket runs -> line-merged global writes
    for (int i = tid; i < cnt; i += 256) {
        const int b = sbuk[i];
        int d0 = gbase[b] + (i - lofs[b]);
        if ((unsigned)d0 < (unsigned)nE) tmp[d0] = stage[i];
    }
}

// ---------------------------------------------------------------------------
// Partition pass B: scatter bucket-grouped records to exact CSR slot.
// Scatter window per bucket ~64KB -> L2-resident -> write merging.
// ---------------------------------------------------------------------------
__global__ __launch_bounds__(256) void partB_kernel(
    const u64* __restrict__ tmp, int* __restrict__ cursor,
    int2* __restrict__ edges_s, int n, int nE) {
    const int i = blockIdx.x * 256 + threadIdx.x;
    if (i >= nE) return;
    const u64 rec = tmp[i];
    int d = (int)(rec & 0x1FFFF);
    d = ((unsigned)d < (unsigned)n) ? d : 0;
    const int s = (int)((rec >> 17) & 0x1FFFF);
    const int ab = (int)((unsigned)(rec >> 34) << 2);
    const int p = atomicAdd(&cursor[d], 1);
    if ((unsigned)p < (unsigned)nE) edges_s[p] = make_int2(s, ab);
}

// Direct fill (fallback when nbuk > 256): plain scattered 8B stores.
__global__ __launch_bounds__(256) void fill_kernel(
    const int* __restrict__ dst, const int* __restrict__ src,
    const float* __restrict__ alpha, int* __restrict__ cursor,
    int2* __restrict__ edges_s, int n, int nE) {
    const int e = blockIdx.x * 256 + threadIdx.x;
    if (e >= nE) return;
    int d = dst[e];
    d = ((unsigned)d < (unsigned)n) ? d : 0;
    const int s = src[e];
    const float a = alpha[e];
    const int p = atomicAdd(&cursor[d], 1);
    if ((unsigned)p < (unsigned)nE) edges_s[p] = make_int2(s, __float_as_int(a));
}

// ---------------------------------------------------------------------------
// Aggregation (atomic-free): one wave per node; 4 edges in parallel
// (quarter-wave = 16 lanes x float4 per edge). Round-13 validated form.
// ---------------------------------------------------------------------------
__global__ __launch_bounds__(256) void agg_kernel(
    const float4* __restrict__ h4, const int2* __restrict__ edges_s,
    const int* __restrict__ offsets, float4* __restrict__ hn4, int n, int nE) {
    const size_t gtid = blockIdx.x * (size_t)256 + threadIdx.x;
    const int v    = (int)(gtid >> 6);
    const int lane = (int)(gtid & 63);
    const int q    = lane >> 4;
    const int c4   = lane & 15;
    if (v >= n) return;

    int b  = offsets[v];
    int e1 = offsets[v + 1];
    if (b < 0) b = 0;
    if (e1 > nE) e1 = nE;

    float4 acc = make_float4(0.f, 0.f, 0.f, 0.f);
    for (int j = b + q; j < e1; j += 4) {
        const int2 ed = edges_s[j];
        int s = ed.x;
        s = ((unsigned)s < (unsigned)n) ? s : 0;
        const float a = __int_as_float(ed.y);
        const float4 hv = h4[(size_t)s * 16 + c4];
        acc.x = fmaf(hv.x, a, acc.x);
        acc.y = fmaf(hv.y, a, acc.y);
        acc.z = fmaf(hv.z, a, acc.z);
        acc.w = fmaf(hv.w, a, acc.w);
    }
    acc.x += __shfl_xor(acc.x, 16, 64); acc.y += __shfl_xor(acc.y, 16, 64);
    acc.z += __shfl_xor(acc.z, 16, 64); acc.w += __shfl_xor(acc.w, 16, 64);
    acc.x += __shfl_xor(acc.x, 32, 64); acc.y += __shfl_xor(acc.y, 32, 64);
    acc.z += __shfl_xor(acc.z, 32, 64); acc.w += __shfl_xor(acc.w, 32, 64);

    if (q == 0) hn4[(size_t)v * 16 + c4] = acc;
}

// ---------------------------------------------------------------------------
// Fallback (ws too small): zero + atomic scatter.
// ---------------------------------------------------------------------------
__global__ __launch_bounds__(256) void zero_kernel(float* __restrict__ p, size_t cnt) {
    const size_t i = blockIdx.x * (size_t)256 + threadIdx.x;
    if (i < cnt) p[i] = 0.f;
}
__global__ __launch_bounds__(256) void scatter_kernel(
    const float4* __restrict__ h4, const float* __restrict__ alpha,
    const int* __restrict__ src, const int* __restrict__ dst,
    float* __restrict__ hn, int nE) {
    const size_t gtid = blockIdx.x * (size_t)256 + threadIdx.x;
    const int eid = (int)(gtid >> 4);
    const int c4  = (int)(gtid & 15);
    if (eid >= nE) return;
    const int   s = src[eid];
    const int   d = dst[eid];
    const float a = alpha[eid];
    const float4 v = h4[(size_t)s * 16 + c4];
    float* p = &hn[(size_t)d * IN_DIM + c4 * 4];
    unsafeAtomicAdd(p + 0, v.x * a);
    unsafeAtomicAdd(p + 1, v.y * a);
    unsafeAtomicAdd(p + 2, v.z * a);
    unsafeAtomicAdd(p + 3, v.w * a);
}

// ---------------------------------------------------------------------------
// Kernel 3: z = ReLU(concat([h, hn]) @ w_w + w_b); out = z / ||z||_2.
// Register-blocked 4 rows x 16 cols per thread (validated round 13).
// ---------------------------------------------------------------------------
__global__ __launch_bounds__(256) void out_kernel(
    const float4* __restrict__ h4, const float4* __restrict__ hn4,
    const float4* __restrict__ ww4, const float4* __restrict__ wb4,
    float4* __restrict__ out4, int n) {
    const size_t gtid = blockIdx.x * (size_t)256 + threadIdx.x;
    const int rg   = (int)(gtid >> 2);
    const int sub  = (int)(gtid & 3);
    const int row0 = rg * 4;
    if (row0 >= n) return;
    const int rmax = (n - row0 < 4) ? (n - row0) : 4;

    float4 acc[4][4];
    #pragma unroll
    for (int r = 0; r < 4; ++r)
        #pragma unroll
        for (int m = 0; m < 4; ++m) acc[r][m] = wb4[sub * 4 + m];

    #pragma unroll
    for (int ph = 0; ph < 2; ++ph) {
        const float4* __restrict__ x4 = (ph == 0) ? h4 : hn4;
        for (int k4 = 0; k4 < 16; ++k4) {
            float4 xv[4];
            #pragma unroll
            for (int r = 0; r < 4; ++r) {
                const int rr = (r < rmax) ? r : 0;
                xv[r] = x4[(size_t)(row0 + rr) * 16 + k4];
            }
            float4 w[4][4];
            #pragma unroll
            for (int j = 0; j < 4; ++j)
                #pragma unroll
                for (int m = 0; m < 4; ++m)
                    w[j][m] = ww4[(ph * 64 + k4 * 4 + j) * 16 + sub * 4 + m];
            #pragma unroll
            for (int j = 0; j < 4; ++j) {
                #pragma unroll
                for (int r = 0; r < 4; ++r) {
                    const float xs = (j == 0) ? xv[r].x : (j == 1) ? xv[r].y
                                   : (j == 2) ? xv[r].z : xv[r].w;
                    #pragma unroll
                    for (int m = 0; m < 4; ++m) {
                        acc[r][m].x = fmaf(xs, w[j][m].x, acc[r][m].x);
                        acc[r][m].y = fmaf(xs, w[j][m].y, acc[r][m].y);
                        acc[r][m].z = fmaf(xs, w[j][m].z, acc[r][m].z);
                        acc[r][m].w = fmaf(xs, w[j][m].w, acc[r][m].w);
                    }
                }
            }
        }
    }

    float sq[4];
    #pragma unroll
    for (int r = 0; r < 4; ++r) {
        float s = 0.f;
        #pragma unroll
        for (int m = 0; m < 4; ++m) {
            acc[r][m].x = fmaxf(acc[r][m].x, 0.f);
            acc[r][m].y = fmaxf(acc[r][m].y, 0.f);
            acc[r][m].z = fmaxf(acc[r][m].z, 0.f);
            acc[r][m].w = fmaxf(acc[r][m].w, 0.f);
            s = fmaf(acc[r][m].x, acc[r][m].x, s);
            s = fmaf(acc[r][m].y, acc[r][m].y, s);
            s = fmaf(acc[r][m].z, acc[r][m].z, s);
            s = fmaf(acc[r][m].w, acc[r][m].w, s);
        }
        sq[r] = s;
    }
    #pragma unroll
    for (int r = 0; r < 4; ++r) {
        sq[r] += __shfl_xor(sq[r], 1, 64);
        sq[r] += __shfl_xor(sq[r], 2, 64);
    }

    #pragma unroll
    for (int r = 0; r < 4; ++r) {
        if (r >= rmax) break;
        const float inv = 1.0f / sqrtf(sq[r]);
        #pragma unroll
        for (int m = 0; m < 4; ++m) {
            nt_f4 v;
            v.x = acc[r][m].x * inv; v.y = acc[r][m].y * inv;
            v.z = acc[r][m].z * inv; v.w = acc[r][m].w * inv;
            __builtin_nontemporal_store(
                v, (nt_f4*)&out4[(size_t)(row0 + r) * 16 + sub * 4 + m]);
        }
    }
}

extern "C" void kernel_launch(void* const* d_in, const int* in_sizes, int n_in,
                              void* d_out, int out_size, void* d_ws, size_t ws_size,
                              hipStream_t stream) {
    const float* feat  = (const float*)d_in[0];
    const float* qw    = (const float*)d_in[1];
    const float* qb    = (const float*)d_in[2];
    const float* ww    = (const float*)d_in[3];
    const float* wb    = (const float*)d_in[4];
    const float* alpha = (const float*)d_in[5];
    const int*   src   = (const int*)d_in[6];
    const int*   dst   = (const int*)d_in[7];
    float* out = (float*)d_out;

    const int n    = in_sizes[0] / IN_DIM;    // 100000
    const int nE   = in_sizes[5];             // 1600000
    const int NB   = (n + 255) / 256;         // 391
    const int NBUK = (n + (1 << BSHIFT) - 1) >> BSHIFT;   // 196

    // workspace layout
    float* h        = (float*)d_ws;                    // n*64 f32
    float* hn       = h + (size_t)n * IN_DIM;          // n*64 f32 (tmp aliases)
    int*   counts   = (int*)(hn + (size_t)n * IN_DIM); // n
    int*   offsets  = counts + n;                      // n+1
    int*   cursor   = offsets + (n + 1);               // n
    int*   blocksums= cursor + n;                      // NB
    int*   bcur     = blocksums + NB;                  // NBUK
    char*  raw      = (char*)(bcur + NBUK);
    int2*  edges_s  = (int2*)(((uintptr_t)raw + 7) & ~(uintptr_t)7);   // nE int2
    const size_t needed = (size_t)((char*)(edges_s + nE) - (char*)d_ws);
    const bool do_csr = ws_size >= needed;
    // tmp for partition pass aliases hn (12.8MB <= 25.6MB; hn written later by agg)
    u64* tmp = (u64*)hn;

    // 0) canary (attribution probe)
    canary_kernel<<<1, 64, 0, stream>>>(offsets, n, nE);

    // 1) projection + zero counts
    {
        const long long t = ((long long)(n + 3) / 4) * 4;
        proj_kernel<<<(int)((t + 255) / 256), 256, 0, stream>>>(
            (const float4*)feat, (const float4*)qw, (const float4*)qb,
            (float4*)h, counts, n);
    }

    if (do_csr) {
        // 2) CSR build
        count_kernel<<<(nE + 255) / 256, 256, 0, stream>>>(dst, counts, n, nE);
        scan1_kernel<<<NB, 256, 0, stream>>>(counts, offsets, blocksums, n);
        scan2_kernel<<<1, 512, 0, stream>>>(blocksums, NB);
        scan3_kernel<<<NB, 256, 0, stream>>>(offsets, cursor, blocksums, bcur, n, nE);
        if (NBUK <= 256) {
            // two-pass radix partition (round-15: fill write-amp fix)
            const int NBA = (nE + EPB - 1) / EPB;
            partA_kernel<<<NBA, 256, 0, stream>>>(
                dst, src, alpha, bcur, tmp, n, nE, NBUK);
            partB_kernel<<<(nE + 255) / 256, 256, 0, stream>>>(
                tmp, cursor, edges_s, n, nE);
        } else {
            fill_kernel<<<(nE + 255) / 256, 256, 0, stream>>>(
                dst, src, alpha, cursor, edges_s, n, nE);
        }
        // 3) atomic-free aggregation
        agg_kernel<<<(int)(((long long)n * 64 + 255) / 256), 256, 0, stream>>>(
            (const float4*)h, edges_s, offsets, (float4*)hn, n, nE);
    } else {
        const size_t cnt = (size_t)n * IN_DIM;
        zero_kernel<<<(int)((cnt + 255) / 256), 256, 0, stream>>>(hn, cnt);
        scatter_kernel<<<(int)(((long long)nE * 16 + 255) / 256), 256, 0, stream>>>(
            (const float4*)h, alpha, src, dst, hn, nE);
    }

    // 4) concat GEMV + ReLU + L2 normalize
    {
        const long long t = ((long long)(n + 3) / 4) * 4;
        out_kernel<<<(int)((t + 255) / 256), 256, 0, stream>>>(
            (const float4*)h, (const float4*)hn, (const float4*)ww,
            (const float4*)wb, (float4*)out, n);
    }
}